// Round 8
// baseline (9811.470 us; speedup 1.0000x reference)
//
#include <hip/hip_runtime.h>

typedef _Float16 half8 __attribute__((ext_vector_type(8)));
typedef float    f32x4 __attribute__((ext_vector_type(4)));
typedef unsigned int u32x2 __attribute__((ext_vector_type(2)));

#define TT 512
#define BB 256
#define INDIM 8
#define HH 512

// ---- workspace layout ----
// floats [0, 131072)             : h1 final fp32 (head input, row-major [b][j])
// halves b16 = ws+131072 floats  : h0h[2] (2x131072), h1h[2] (2x131072)
//                                  -- h buffers are BLOCKED: [32 c][256 b][16 cols]
//                                  Wpk [32 c][144 nl][512 k]
// bytes 6291456                  : flags, 8 groups x 32 ints (one 128B line each)

__global__ void prep_kernel(const float* __restrict__ Whh0,
                            const float* __restrict__ Wih1,
                            const float* __restrict__ Whh1,
                            float* __restrict__ ws)
{
    const int NW = 32*144*512;                 // 2359296 packed weight halves
    _Float16* b16 = (_Float16*)(ws + 131072);
    _Float16* Wpk = b16 + 524288;
    int* flags = (int*)((char*)ws + 6291456);
    long long idx = (long long)blockIdx.x*256 + threadIdx.x;
    if (idx < NW) {
        int e   = (int)idx;
        int c   = e / (144*512);               // col-chunk 0..31 -> cols [c*16, c*16+16)
        int rem = e % (144*512);
        int nl  = rem >> 9;                    // 0..143 = g9*16 + m
        int k   = rem & 511;                   // logical k
        int g9  = nl >> 4;
        int m   = nl & 15;
        int j   = c*16 + m;
        float v;
        if      (g9 < 3) v = Whh0[(size_t)(g9*HH + j)*HH + k];
        else if (g9 < 6) v = Wih1[(size_t)((g9-3)*HH + j)*HH + k];
        else             v = Whh1[(size_t)((g9-6)*HH + j)*HH + k];
        Wpk[e] = (_Float16)v;
    } else if (idx < NW + 524288) {
        b16[idx - NW] = (_Float16)0.0f;        // zero all 4 f16 h buffers
    } else if (idx < NW + 524288 + 512) {
        flags[idx - NW - 524288] = 0;          // zero flag slots
    } else if (idx < NW + 524288 + 512 + 131072) {
        ws[idx - (NW + 524288 + 512)] = 1.0e-3f;  // sentinel canary
    }
}

// 128 blocks x 256 threads (4 waves), PLAIN launch.
// bg = blk>>4 (batch group of 32 rows), jg = blk&15 (col group of 32).
// IDENTICAL to round-7 (passed, 9732 us) EXCEPT the rendezvous wait:
//   - hot poll (no s_sleep)  - ALL 4 waves poll  - no exit __syncthreads.
// Single-hypothesis test: the device sits ~94% idle (1 polling wave in s_sleep,
// 3 waves parked at a barrier) -> DVFS drops engine clock -> every latency in
// the serial exchange chain inflates ~4x (explains 18.8us step vs ~5us model
// AND the 3-4x run-to-run spread of identical dispatches). Keeping all waves
// issuing ops through the wait should hold clocks up. Per-wave self-confirm
// is strictly stronger gating than wave0-confirm+barrier; stg/WlL have no
// cross-wave hazards, so dropping the exit barrier is safe.
__global__ void __launch_bounds__(256, 1)
gru_main(const float* __restrict__ x,
         const float* __restrict__ Wih0, const float* __restrict__ bih0,
         const float* __restrict__ bhh0, const float* __restrict__ bih1,
         const float* __restrict__ bhh1, float* __restrict__ ws)
{
    __shared__ __align__(16) _Float16 WlL[2*144*96];   // 55296 B: k-steps 0..2, both chunks
    __shared__ __align__(16) _Float16 stg[4][256];     // 2 KB: per-wave transpose tiles

    const int tid = threadIdx.x;
    const int blk = blockIdx.x;        // 0..127
    const int jg  = blk & 15;          // col group (32 cols)
    const int bg  = blk >> 4;          // batch group (32 rows)

    float* h1f = ws;
    _Float16* b16 = (_Float16*)(ws + 131072);
    _Float16* h0h[2] = { b16,          b16 + 131072 };
    _Float16* h1h[2] = { b16 + 262144, b16 + 393216 };
    const _Float16* Wpk = b16 + 524288;

    int* grpflags = (int*)((char*)ws + 6291456) + bg*32;  // 128B line/group
    int* slotp    = grpflags + jg;
    const int* pollp = grpflags + (tid & 15);   // every wave covers all 16 slots

    // ---- one-time LDS fill: k-steps 0..2 for both chunks, XOR-swizzled ----
    for (int t = tid; t < 2*144*12; t += 256) {
        int c   = t / (144*12);
        int rem = t % (144*12);
        int nl  = rem / 12, gg = rem % 12;
        int slot = gg ^ ((nl >> 1) & 3);
        *(float4*)&WlL[c*13824 + nl*96 + slot*8] =
            *(const float4*)&Wpk[((size_t)(jg*2 + c)*144 + nl)*512 + gg*8];
    }
    __syncthreads();

    const int lane = tid & 63;
    const int wv   = tid >> 6;          // 4 waves: ct = wv&1 (col chunk), rt = wv>>1 (row tile)
    const int ct   = wv & 1;
    const int rt   = wv >> 1;
    const int m    = lane & 15;         // A,B frag row / j-local
    const int q    = lane >> 4;         // 0..3
    const int key  = (m >> 1) & 3;      // LDS swizzle key (matches fill)
    const int j    = jg*32 + ct*16 + m;
    const int bb   = bg*32 + rt*16;     // wave's batch base

    const _Float16* WpkB = Wpk + (size_t)(jg*2 + ct)*(144*512);
    const _Float16* WlLc = WlL + ct*13824;

    // per-lane A offset into blocked layout [cc][256][16]:
    // k = s*32 + q*8  ->  chunk cc = 2s + (q>>1), in-chunk col (q&1)*8
    const int aoff = ((q>>1)*256 + bb + m)*16 + (q&1)*8;
    // this wave's contiguous 512B store region (chunk 2jg+ct, rows bb..bb+16)
    const size_t stbase = ((size_t)(2*jg + ct)*256 + bb)*16;

    // ---- per-lane constants ----
    float w0[3][8];
    #pragma unroll
    for (int g = 0; g < 3; ++g)
        #pragma unroll
        for (int kk = 0; kk < 8; ++kk)
            w0[g][kk] = Wih0[(size_t)(g*HH + j)*INDIM + kk];
    const float br0  = bih0[j]      + bhh0[j];
    const float bz0  = bih0[HH+j]   + bhh0[HH+j];
    const float bni0 = bih0[2*HH+j];
    const float bnh0 = bhh0[2*HH+j];
    const float br1  = bih1[j]      + bhh1[j];
    const float bz1  = bih1[HH+j]   + bhh1[HH+j];
    const float bni1 = bih1[2*HH+j];
    const float bnh1 = bhh1[2*HH+j];

    // ---- VGPR B-cache: k-steps 3..4 ----
    half8 Bc[2][9];
    #pragma unroll
    for (int s = 0; s < 2; ++s)
        #pragma unroll
        for (int g = 0; g < 9; ++g)
            Bc[s][g] = *(const half8*)&WpkB[(size_t)(g*16+m)*512 + (3+s)*32 + q*8];

    // fp32 hidden state carried in registers (lane owns rows q*4+r, col j)
    float h0pr[4] = {0.f,0.f,0.f,0.f};
    float h1pr[4] = {0.f,0.f,0.f,0.f};

    for (int p = 0; p <= TT; ++p) {
        const _Float16* h0p = h0h[(p+1)&1];   // h0[p-1]
        const _Float16* h1p = h1h[p&1];       // h1[p-2]
        const _Float16* a0base = h0p + aoff;
        const _Float16* a1base = h1p + aoff;

        // ---- A fragments: 32 LLC-coherent loads in flight ----
        half8 a0s[16], a1s[16];
        #pragma unroll
        for (int s = 0; s < 16; ++s) {
            asm volatile("global_load_dwordx4 %0, %1, off sc0 sc1"
                         : "=v"(a0s[s]) : "v"(a0base + s*8192));
            asm volatile("global_load_dwordx4 %0, %1, off sc0 sc1"
                         : "=v"(a1s[s]) : "v"(a1base + s*8192));
        }
        // ---- x prefetch for this step's epilogue (plain cacheable loads) ----
        f32x4 xA[4], xB[4];
        {
            const size_t psafe = (p < TT) ? (size_t)p : 0;
            #pragma unroll
            for (int r = 0; r < 4; ++r) {
                const float* xv = x + (psafe*BB + (size_t)(bb + q*4 + r))*INDIM;
                asm volatile("global_load_dwordx4 %0, %1, off" : "=v"(xA[r]) : "v"(xv));
                asm volatile("global_load_dwordx4 %0, %1, off" : "=v"(xB[r]) : "v"(xv + 4));
            }
        }
        asm volatile("s_waitcnt vmcnt(0)"
            : "+v"(a0s[0]),"+v"(a0s[1]),"+v"(a0s[2]),"+v"(a0s[3]),
              "+v"(a0s[4]),"+v"(a0s[5]),"+v"(a0s[6]),"+v"(a0s[7]),
              "+v"(a0s[8]),"+v"(a0s[9]),"+v"(a0s[10]),"+v"(a0s[11]),
              "+v"(a0s[12]),"+v"(a0s[13]),"+v"(a0s[14]),"+v"(a0s[15]));
        asm volatile(""
            : "+v"(a1s[0]),"+v"(a1s[1]),"+v"(a1s[2]),"+v"(a1s[3]),
              "+v"(a1s[4]),"+v"(a1s[5]),"+v"(a1s[6]),"+v"(a1s[7]),
              "+v"(a1s[8]),"+v"(a1s[9]),"+v"(a1s[10]),"+v"(a1s[11]),
              "+v"(a1s[12]),"+v"(a1s[13]),"+v"(a1s[14]),"+v"(a1s[15]));
        asm volatile(""
            : "+v"(xA[0]),"+v"(xA[1]),"+v"(xA[2]),"+v"(xA[3]),
              "+v"(xB[0]),"+v"(xB[1]),"+v"(xB[2]),"+v"(xB[3]));

        f32x4 acc[9];
        #pragma unroll
        for (int g = 0; g < 9; ++g) acc[g] = (f32x4){0.f,0.f,0.f,0.f};

        // ---- k-steps 0..2: B from LDS ----
        #pragma unroll
        for (int s = 0; s < 3; ++s) {
            #pragma unroll
            for (int g = 0; g < 9; ++g) {
                half8 bf = *(const half8*)&WlLc[(g*16+m)*96 + (((s*4+q) ^ key))*8];
                acc[g] = __builtin_amdgcn_mfma_f32_16x16x32_f16((g < 6) ? a0s[s] : a1s[s], bf, acc[g], 0, 0, 0);
            }
        }
        // ---- k-steps 3..4: B from VGPR cache ----
        #pragma unroll
        for (int s = 0; s < 2; ++s) {
            #pragma unroll
            for (int g = 0; g < 9; ++g)
                acc[g] = __builtin_amdgcn_mfma_f32_16x16x32_f16((g < 6) ? a0s[3+s] : a1s[3+s], Bc[s][g], acc[g], 0, 0, 0);
        }
        // ---- k-steps 5..15: B pipelined one step ahead from L2 ----
        half8 nb[9];
        #pragma unroll
        for (int g = 0; g < 9; ++g)
            nb[g] = *(const half8*)&WpkB[(size_t)(g*16+m)*512 + 5*32 + q*8];
        #pragma unroll
        for (int s = 5; s < 16; ++s) {
            half8 cb[9];
            #pragma unroll
            for (int g = 0; g < 9; ++g) cb[g] = nb[g];
            if (s < 15) {
                #pragma unroll
                for (int g = 0; g < 9; ++g)
                    nb[g] = *(const half8*)&WpkB[(size_t)(g*16+m)*512 + (s+1)*32 + q*8];
            }
            #pragma unroll
            for (int g = 0; g < 9; ++g)
                acc[g] = __builtin_amdgcn_mfma_f32_16x16x32_f16((g < 6) ? a0s[s] : a1s[s], cb[g], acc[g], 0, 0, 0);
        }

        // ---- fused epilogues; h stores: LDS transpose -> one dwordx2/lane ----
        _Float16* h0n = h0h[p&1];
        _Float16* h1n = h1h[(p+1)&1];
        if (p < TT) {
            #pragma unroll
            for (int r = 0; r < 4; ++r) {
                const int b = bb + q*4 + r;
                f32x4 xa = xA[r];
                f32x4 xb = xB[r];
                float gr = xa[0]*w0[0][0]+xa[1]*w0[0][1]+xa[2]*w0[0][2]+xa[3]*w0[0][3]
                         + xb[0]*w0[0][4]+xb[1]*w0[0][5]+xb[2]*w0[0][6]+xb[3]*w0[0][7];
                float gz = xa[0]*w0[1][0]+xa[1]*w0[1][1]+xa[2]*w0[1][2]+xa[3]*w0[1][3]
                         + xb[0]*w0[1][4]+xb[1]*w0[1][5]+xb[2]*w0[1][6]+xb[3]*w0[1][7];
                float gn = xa[0]*w0[2][0]+xa[1]*w0[2][1]+xa[2]*w0[2][2]+xa[3]*w0[2][3]
                         + xb[0]*w0[2][4]+xb[1]*w0[2][5]+xb[2]*w0[2][6]+xb[3]*w0[2][7];
                float rg = 1.f/(1.f + __expf(-(gr + acc[0][r] + br0)));
                float zg = 1.f/(1.f + __expf(-(gz + acc[1][r] + bz0)));
                float ng = tanhf(gn + bni0 + rg*(acc[2][r] + bnh0));
                float hv = (1.f - zg)*ng + zg*h0pr[r];
                h0pr[r] = hv;
                stg[wv][(q*4+r)*16 + m] = (_Float16)hv;   // transpose tile
            }
            u32x2 wd = *(const u32x2*)&stg[wv][lane*4];    // 8B/lane, 512B/wave
            asm volatile("global_store_dwordx2 %0, %1, off sc0 sc1"
                         :: "v"(h0n + stbase + lane*4), "v"(wd) : "memory");
        }
        if (p >= 1) {
            #pragma unroll
            for (int r = 0; r < 4; ++r) {
                const int b = bb + q*4 + r;
                float rg = 1.f/(1.f + __expf(-(acc[3][r] + acc[6][r] + br1)));
                float zg = 1.f/(1.f + __expf(-(acc[4][r] + acc[7][r] + bz1)));
                float ng = tanhf(acc[5][r] + bni1 + rg*(acc[8][r] + bnh1));
                float hv = (1.f - zg)*ng + zg*h1pr[r];
                h1pr[r] = hv;
                stg[wv][(q*4+r)*16 + m] = (_Float16)hv;   // reuse tile (in-order DS)
                if (p == TT) h1f[(size_t)b*HH + j] = hv;  // kernel-boundary flush
            }
            u32x2 wd = *(const u32x2*)&stg[wv][lane*4];
            asm volatile("global_store_dwordx2 %0, %1, off sc0 sc1"
                         :: "v"(h1n + stbase + lane*4), "v"(wd) : "memory");
        }

        // ---- rendezvous: drain + barrier + flag, then ALL waves HOT-poll ----
        // No s_sleep, no exit barrier: each wave independently observes all 16
        // flags >= p+1 and proceeds (stronger gating than wave0+barrier).
        if (p < TT) {
            asm volatile("s_waitcnt vmcnt(0)" ::: "memory");
            __syncthreads();
            if (tid == 0) {
                int pv = p + 1;
                asm volatile("global_store_dword %0, %1, off sc0 sc1"
                             :: "v"(slotp), "v"(pv) : "memory");
            }
            while (true) {
                int v;
                asm volatile("global_load_dword %0, %1, off sc0 sc1"
                             : "=v"(v) : "v"(pollp));
                asm volatile("s_waitcnt vmcnt(0)" : "+v"(v));
                if (__all(v > p)) break;
            }
        }
    }
}

__global__ void head_kernel(const float* __restrict__ ws,
                            const float* __restrict__ Wout,
                            const float* __restrict__ bout,
                            float* __restrict__ out)
{
    const float* h1 = ws;               // h1[511] fp32
    int b = blockIdx.x;
    int lane = threadIdx.x;             // 64
    for (int o = 0; o < 5; ++o) {
        float s = 0.f;
        for (int k = lane; k < HH; k += 64)
            s += h1[(size_t)b*HH + k] * Wout[(size_t)o*HH + k];
        for (int off = 32; off > 0; off >>= 1)
            s += __shfl_xor(s, off, 64);
        if (lane == 0) out[b*5 + o] = s + bout[o];
    }
}

extern "C" void kernel_launch(void* const* d_in, const int* in_sizes, int n_in,
                              void* d_out, int out_size, void* d_ws, size_t ws_size,
                              hipStream_t stream) {
    const float* x    = (const float*)d_in[0];
    const float* Wih0 = (const float*)d_in[1];
    const float* Whh0 = (const float*)d_in[2];
    const float* bih0 = (const float*)d_in[3];
    const float* bhh0 = (const float*)d_in[4];
    const float* Wih1 = (const float*)d_in[5];
    const float* Whh1 = (const float*)d_in[6];
    const float* bih1 = (const float*)d_in[7];
    const float* bhh1 = (const float*)d_in[8];
    const float* Wout = (const float*)d_in[9];
    const float* bout = (const float*)d_in[10];
    float* out = (float*)d_out;
    float* ws  = (float*)d_ws;   // needs ~6.3 MB

    // 1) pack weights to f16 + zero f16 state + zero flags + sentinel h1f
    const long long total = 32LL*144*512 + 524288 + 512 + 131072;
    int pblocks = (int)((total + 255) / 256);
    hipLaunchKernelGGL(prep_kernel, dim3(pblocks), dim3(256), 0, stream,
                       Whh0, Wih1, Whh1, ws);

    // 2) persistent recurrence — plain launch, 128 blocks x 256 thr
    hipLaunchKernelGGL(gru_main, dim3(128), dim3(256), 0, stream,
                       x, Wih0, bih0, bhh0, bih1, bhh1, ws);

    // 3) linear head
    hipLaunchKernelGGL(head_kernel, dim3(256), dim3(64), 0, stream,
                       (const float*)ws, Wout, bout, out);
}

// Round 9
// 6831.013 us; speedup vs baseline: 1.4363x; 1.4363x over previous
//
#include <hip/hip_runtime.h>

typedef _Float16 half8 __attribute__((ext_vector_type(8)));
typedef float    f32x4 __attribute__((ext_vector_type(4)));

#define TT 512
#define BB 256
#define INDIM 8
#define HH 512

// ---- workspace layout ----
// floats [0, 131072)             : h1 final fp32 (head input, row-major [b][j])
// halves b16 = ws+131072 floats  : h0h[2] (2x131072), h1h[2] (2x131072)  (ROW-MAJOR [b][512])
//                                  Wpk [32 c][144 nl][512 k]  (c = 16-col chunk)
// bytes 6291456                  : flag0: 8 groups x 32 ints; flag1: 8 groups x 32 ints (512 ints)

__global__ void prep_kernel(const float* __restrict__ Whh0,
                            const float* __restrict__ Wih1,
                            const float* __restrict__ Whh1,
                            float* __restrict__ ws)
{
    const int NW = 32*144*512;                 // 2359296 packed weight halves
    _Float16* b16 = (_Float16*)(ws + 131072);
    _Float16* Wpk = b16 + 524288;
    int* flags = (int*)((char*)ws + 6291456);
    long long idx = (long long)blockIdx.x*256 + threadIdx.x;
    if (idx < NW) {
        int e   = (int)idx;
        int c   = e / (144*512);               // col-chunk 0..31 -> cols [c*16, c*16+16)
        int rem = e % (144*512);
        int nl  = rem >> 9;                    // 0..143 = g9*16 + m
        int k   = rem & 511;
        int g9  = nl >> 4;
        int m   = nl & 15;
        int j   = c*16 + m;
        float v;
        if      (g9 < 3) v = Whh0[(size_t)(g9*HH + j)*HH + k];
        else if (g9 < 6) v = Wih1[(size_t)((g9-3)*HH + j)*HH + k];
        else             v = Whh1[(size_t)((g9-6)*HH + j)*HH + k];
        Wpk[e] = (_Float16)v;
    } else if (idx < NW + 524288) {
        b16[idx - NW] = (_Float16)0.0f;        // zero all 4 f16 h buffers
    } else if (idx < NW + 524288 + 512) {
        flags[idx - NW - 524288] = 0;          // zero flag0 + flag1 slots
    } else if (idx < NW + 524288 + 512 + 131072) {
        ws[idx - (NW + 524288 + 512)] = 1.0e-3f;  // sentinel canary
    }
}

// 128 blocks x 256 threads (4 waves). bg = blk>>4 (32 batch rows), jg = blk&15 (32 cols).
// SPLIT-PHASE iteration (the structural change this round):
//  PHASE 1 (critical chain): a0 loads (h0[p-1]) -> gates 0-2 GEMM with B entirely
//    from LDS -> h0 epilogue -> h0 store -> drain -> publish flag0=p+1.
//  PHASE 2 (shadow, runs while peers are in their phase 1): flag1 gate -> a1 loads
//    (h1[p-2]) -> gates 3-5 (LDS ks0-7 + streamed ks8-15) -> gates 6-8 (VGPR-cached
//    ks0-11 + streamed ks12-15) -> h1[p-1] epilogue -> h1 store -> drain -> publish
//    flag1=p+1 -> x prefetch -> poll flag0 for next iteration.
// Dist-2 buffer safety: flag0=p+1 implies that block's a0 reads of h0[p-1] completed
// (loads waited before GEMM before store before publish); a writer of h0[p+1] is
// gated on ALL flag0>=p+1, so no overwrite race. Same argument for flag1/h1.
__global__ void __launch_bounds__(256, 1)
gru_main(const float* __restrict__ x,
         const float* __restrict__ Wih0, const float* __restrict__ bih0,
         const float* __restrict__ bhh0, const float* __restrict__ bih1,
         const float* __restrict__ bhh1, float* __restrict__ ws)
{
    __shared__ __align__(16) _Float16 Wl[73728];   // 147456 B: gates0-2 all k + gates3-5 k0-255

    const int tid = threadIdx.x;
    const int blk = blockIdx.x;        // 0..127
    const int jg  = blk & 15;          // col group (32 cols = chunks 2jg, 2jg+1)
    const int bg  = blk >> 4;          // batch group (32 rows)

    float* h1f = ws;
    _Float16* b16 = (_Float16*)(ws + 131072);
    _Float16* h0h[2] = { b16,          b16 + 131072 };
    _Float16* h1h[2] = { b16 + 262144, b16 + 393216 };
    const _Float16* Wpk = b16 + 524288;

    volatile int* flag0row = (volatile int*)((char*)ws + 6291456) + bg*32;
    volatile int* flag1row = (volatile int*)((char*)ws + 6291456) + 256 + bg*32;

    // ---- one-time LDS fill ----
    // Region A: gates 0-2 (Whh0), both chunks, all 512 k: [2 c][48 nl][64 granules of 16B],
    //   granule slot XOR-swizzled by row (slot = g ^ (nl&7)) for conflict-free ds_read_b128.
    for (int t = tid; t < 2*48*64; t += 256) {
        int c = t / 3072, rem = t % 3072, nl = rem >> 6, g = rem & 63;
        int slot = g ^ (nl & 7);
        *(float4*)&Wl[c*24576 + nl*512 + slot*8] =
            *(const float4*)&Wpk[((size_t)(jg*2 + c)*144 + nl)*512 + g*8];
    }
    // Region B: gates 3-5 (Wih1), both chunks, k-steps 0..7 (k<256): [2 c][48 nl][32 granules]
    for (int t = tid; t < 2*48*32; t += 256) {
        int c = t / 1536, rem = t % 1536, nl = rem >> 5, g = rem & 31;
        int slot = g ^ (nl & 7);
        *(float4*)&Wl[49152 + c*12288 + nl*256 + slot*8] =
            *(const float4*)&Wpk[((size_t)(jg*2 + c)*144 + 48 + nl)*512 + g*8];
    }
    __syncthreads();

    const int lane = tid & 63;
    const int wv   = tid >> 6;          // ct = wv&1 (col chunk), rt = wv>>1 (row tile)
    const int ct   = wv & 1;
    const int rt   = wv >> 1;
    const int m    = lane & 15;
    const int q    = lane >> 4;
    const int key  = m & 7;             // LDS swizzle key (matches fill: nl&7 = m&7)
    const int j    = jg*32 + ct*16 + m;
    const int bb   = bg*32 + rt*16;

    const _Float16* WpkB = Wpk + (size_t)(jg*2 + ct)*(144*512);
    const _Float16* WlA  = Wl + ct*24576;
    const _Float16* WlB  = Wl + 49152 + ct*12288;

    // ---- per-lane constants ----
    float w0[3][8];
    #pragma unroll
    for (int g = 0; g < 3; ++g)
        #pragma unroll
        for (int kk = 0; kk < 8; ++kk)
            w0[g][kk] = Wih0[(size_t)(g*HH + j)*INDIM + kk];
    const float br0  = bih0[j]      + bhh0[j];
    const float bz0  = bih0[HH+j]   + bhh0[HH+j];
    const float bni0 = bih0[2*HH+j];
    const float bnh0 = bhh0[2*HH+j];
    const float br1  = bih1[j]      + bhh1[j];
    const float bz1  = bih1[HH+j]   + bhh1[HH+j];
    const float bni1 = bih1[2*HH+j];
    const float bnh1 = bhh1[2*HH+j];

    // ---- VGPR B-cache: gates 6-8 (Whh1), k-steps 0..11 (144 VGPR; 1 wave/SIMD -> budget 512) ----
    half8 Bc[12][3];
    #pragma unroll
    for (int s = 0; s < 12; ++s)
        #pragma unroll
        for (int gg = 0; gg < 3; ++gg)
            Bc[s][gg] = *(const half8*)&WpkB[(size_t)(96 + gg*16 + m)*512 + s*32 + q*8];

    float h0pr[4] = {0.f,0.f,0.f,0.f};
    float h1pr[4] = {0.f,0.f,0.f,0.f};

    // ---- x prefetch for p=0 ----
    f32x4 xA[4], xB[4];
    {
        #pragma unroll
        for (int r = 0; r < 4; ++r) {
            const float* xv = x + (size_t)(bb + q*4 + r)*INDIM;
            asm volatile("global_load_dwordx4 %0, %1, off" : "=v"(xA[r]) : "v"(xv));
            asm volatile("global_load_dwordx4 %0, %1, off" : "=v"(xB[r]) : "v"(xv + 4));
        }
    }

    for (int p = 0; p <= TT; ++p) {
        // ================= PHASE 1 — critical chain =================
        const _Float16* h0p    = h0h[(p+1)&1];             // h0[p-1]
        const _Float16* a0base = h0p + (size_t)(bb + m)*HH + q*8;
        half8 a0s[16];
        #pragma unroll
        for (int s = 0; s < 16; ++s)
            asm volatile("global_load_dwordx4 %0, %1, off sc0 sc1"
                         : "=v"(a0s[s]) : "v"(a0base + s*32));
        asm volatile("s_waitcnt vmcnt(0)"
            : "+v"(a0s[0]),"+v"(a0s[1]),"+v"(a0s[2]),"+v"(a0s[3]),
              "+v"(a0s[4]),"+v"(a0s[5]),"+v"(a0s[6]),"+v"(a0s[7]),
              "+v"(a0s[8]),"+v"(a0s[9]),"+v"(a0s[10]),"+v"(a0s[11]),
              "+v"(a0s[12]),"+v"(a0s[13]),"+v"(a0s[14]),"+v"(a0s[15]));
        asm volatile(""
            : "+v"(xA[0]),"+v"(xA[1]),"+v"(xA[2]),"+v"(xA[3]),
              "+v"(xB[0]),"+v"(xB[1]),"+v"(xB[2]),"+v"(xB[3]));

        f32x4 acc0[3];
        #pragma unroll
        for (int g = 0; g < 3; ++g) acc0[g] = (f32x4){0.f,0.f,0.f,0.f};
        #pragma unroll
        for (int s = 0; s < 16; ++s) {
            #pragma unroll
            for (int g = 0; g < 3; ++g) {
                half8 bf = *(const half8*)&WlA[(g*16+m)*512 + (((s*4+q) ^ key))*8];
                acc0[g] = __builtin_amdgcn_mfma_f32_16x16x32_f16(a0s[s], bf, acc0[g], 0, 0, 0);
            }
        }

        _Float16* h0n = h0h[p&1];
        if (p < TT) {
            #pragma unroll
            for (int r = 0; r < 4; ++r) {
                const int b = bb + q*4 + r;
                f32x4 xa = xA[r], xb = xB[r];
                float gr = xa[0]*w0[0][0]+xa[1]*w0[0][1]+xa[2]*w0[0][2]+xa[3]*w0[0][3]
                         + xb[0]*w0[0][4]+xb[1]*w0[0][5]+xb[2]*w0[0][6]+xb[3]*w0[0][7];
                float gz = xa[0]*w0[1][0]+xa[1]*w0[1][1]+xa[2]*w0[1][2]+xa[3]*w0[1][3]
                         + xb[0]*w0[1][4]+xb[1]*w0[1][5]+xb[2]*w0[1][6]+xb[3]*w0[1][7];
                float gn = xa[0]*w0[2][0]+xa[1]*w0[2][1]+xa[2]*w0[2][2]+xa[3]*w0[2][3]
                         + xb[0]*w0[2][4]+xb[1]*w0[2][5]+xb[2]*w0[2][6]+xb[3]*w0[2][7];
                float rg = 1.f/(1.f + __expf(-(gr + acc0[0][r] + br0)));
                float zg = 1.f/(1.f + __expf(-(gz + acc0[1][r] + bz0)));
                float ng = tanhf(gn + bni0 + rg*(acc0[2][r] + bnh0));
                float hv = (1.f - zg)*ng + zg*h0pr[r];
                h0pr[r] = hv;
                _Float16 hv16 = (_Float16)hv;
                asm volatile("global_store_short %0, %1, off sc0 sc1"
                             :: "v"(h0n + (size_t)b*HH + j), "v"(hv16) : "memory");
            }
            asm volatile("s_waitcnt vmcnt(0)" ::: "memory");
            __syncthreads();
            if (tid == 0) flag0row[jg] = p + 1;        // h0[p] published EARLY
        }

        // ================= PHASE 2 — shadow work =================
        // Gate on h1[p-2] visibility (published mid-window of iteration p-1).
        while (true) {
            int v = flag1row[lane & 15];
            if (__all(v >= p)) break;
            __builtin_amdgcn_s_sleep(1);
        }
        const _Float16* h1p    = h1h[p&1];                 // h1[p-2]
        const _Float16* a1base = h1p + (size_t)(bb + m)*HH + q*8;
        half8 a1s[16];
        #pragma unroll
        for (int s = 0; s < 16; ++s)
            asm volatile("global_load_dwordx4 %0, %1, off sc0 sc1"
                         : "=v"(a1s[s]) : "v"(a1base + s*32));

        f32x4 acc1[6];   // [0..2] gates 3-5 (Wih1*h0[p-1]); [3..5] gates 6-8 (Whh1*h1[p-2])
        #pragma unroll
        for (int g = 0; g < 6; ++g) acc1[g] = (f32x4){0.f,0.f,0.f,0.f};

        // gates 3-5: k-steps 0-7 from LDS, 8-15 streamed from L2 (hides a1 latency)
        #pragma unroll
        for (int s = 0; s < 8; ++s) {
            #pragma unroll
            for (int gg = 0; gg < 3; ++gg) {
                half8 bf = *(const half8*)&WlB[(gg*16+m)*256 + (((s*4+q) ^ key))*8];
                acc1[gg] = __builtin_amdgcn_mfma_f32_16x16x32_f16(a0s[s], bf, acc1[gg], 0, 0, 0);
            }
        }
        #pragma unroll
        for (int s = 8; s < 16; ++s) {
            #pragma unroll
            for (int gg = 0; gg < 3; ++gg) {
                half8 bf = *(const half8*)&WpkB[(size_t)(48 + gg*16 + m)*512 + s*32 + q*8];
                acc1[gg] = __builtin_amdgcn_mfma_f32_16x16x32_f16(a0s[s], bf, acc1[gg], 0, 0, 0);
            }
        }
        asm volatile("s_waitcnt vmcnt(0)"
            : "+v"(a1s[0]),"+v"(a1s[1]),"+v"(a1s[2]),"+v"(a1s[3]),
              "+v"(a1s[4]),"+v"(a1s[5]),"+v"(a1s[6]),"+v"(a1s[7]),
              "+v"(a1s[8]),"+v"(a1s[9]),"+v"(a1s[10]),"+v"(a1s[11]),
              "+v"(a1s[12]),"+v"(a1s[13]),"+v"(a1s[14]),"+v"(a1s[15]));
        // gates 6-8: k-steps 0-11 from VGPR cache, 12-15 streamed
        #pragma unroll
        for (int s = 0; s < 12; ++s) {
            #pragma unroll
            for (int gg = 0; gg < 3; ++gg)
                acc1[3+gg] = __builtin_amdgcn_mfma_f32_16x16x32_f16(a1s[s], Bc[s][gg], acc1[3+gg], 0, 0, 0);
        }
        #pragma unroll
        for (int s = 12; s < 16; ++s) {
            #pragma unroll
            for (int gg = 0; gg < 3; ++gg) {
                half8 bf = *(const half8*)&WpkB[(size_t)(96 + gg*16 + m)*512 + s*32 + q*8];
                acc1[3+gg] = __builtin_amdgcn_mfma_f32_16x16x32_f16(a1s[s], bf, acc1[3+gg], 0, 0, 0);
            }
        }

        _Float16* h1n = h1h[(p+1)&1];
        if (p >= 1) {
            #pragma unroll
            for (int r = 0; r < 4; ++r) {
                const int b = bb + q*4 + r;
                float rg = 1.f/(1.f + __expf(-(acc1[0][r] + acc1[3][r] + br1)));
                float zg = 1.f/(1.f + __expf(-(acc1[1][r] + acc1[4][r] + bz1)));
                float ng = tanhf(acc1[2][r] + bni1 + rg*(acc1[5][r] + bnh1));
                float hv = (1.f - zg)*ng + zg*h1pr[r];
                h1pr[r] = hv;
                _Float16 hv16 = (_Float16)hv;
                asm volatile("global_store_short %0, %1, off sc0 sc1"
                             :: "v"(h1n + (size_t)b*HH + j), "v"(hv16) : "memory");
                if (p == TT) h1f[(size_t)b*HH + j] = hv;   // kernel-boundary flush
            }
        }

        if (p < TT) {
            asm volatile("s_waitcnt vmcnt(0)" ::: "memory");
            __syncthreads();
            if (tid == 0) flag1row[jg] = p + 1;        // h1[p-1] published

            // x prefetch for p+1 (in flight across the poll; drained next phase 1)
            {
                const size_t psafe = (p + 1 < TT) ? (size_t)(p + 1) : (size_t)(TT - 1);
                #pragma unroll
                for (int r = 0; r < 4; ++r) {
                    const float* xv = x + (psafe*BB + (size_t)(bb + q*4 + r))*INDIM;
                    asm volatile("global_load_dwordx4 %0, %1, off" : "=v"(xA[r]) : "v"(xv));
                    asm volatile("global_load_dwordx4 %0, %1, off" : "=v"(xB[r]) : "v"(xv + 4));
                }
            }
            // end-of-window: wait for all peers' flag0 (usually long set)
            if (tid < 64) {
                while (true) {
                    int v = flag0row[lane & 15];
                    if (__all(v > p)) break;
                    __builtin_amdgcn_s_sleep(1);
                }
            }
            __syncthreads();
        }
    }
}

__global__ void head_kernel(const float* __restrict__ ws,
                            const float* __restrict__ Wout,
                            const float* __restrict__ bout,
                            float* __restrict__ out)
{
    const float* h1 = ws;               // h1[511] fp32
    int b = blockIdx.x;
    int lane = threadIdx.x;             // 64
    for (int o = 0; o < 5; ++o) {
        float s = 0.f;
        for (int k = lane; k < HH; k += 64)
            s += h1[(size_t)b*HH + k] * Wout[(size_t)o*HH + k];
        for (int off = 32; off > 0; off >>= 1)
            s += __shfl_xor(s, off, 64);
        if (lane == 0) out[b*5 + o] = s + bout[o];
    }
}

extern "C" void kernel_launch(void* const* d_in, const int* in_sizes, int n_in,
                              void* d_out, int out_size, void* d_ws, size_t ws_size,
                              hipStream_t stream) {
    const float* x    = (const float*)d_in[0];
    const float* Wih0 = (const float*)d_in[1];
    const float* Whh0 = (const float*)d_in[2];
    const float* bih0 = (const float*)d_in[3];
    const float* bhh0 = (const float*)d_in[4];
    const float* Wih1 = (const float*)d_in[5];
    const float* Whh1 = (const float*)d_in[6];
    const float* bih1 = (const float*)d_in[7];
    const float* bhh1 = (const float*)d_in[8];
    const float* Wout = (const float*)d_in[9];
    const float* bout = (const float*)d_in[10];
    float* out = (float*)d_out;
    float* ws  = (float*)d_ws;   // needs ~6.3 MB

    // 1) pack weights to f16 + zero f16 state + zero flags + sentinel h1f
    const long long total = 32LL*144*512 + 524288 + 512 + 131072;
    int pblocks = (int)((total + 255) / 256);
    hipLaunchKernelGGL(prep_kernel, dim3(pblocks), dim3(256), 0, stream,
                       Whh0, Wih1, Whh1, ws);

    // 2) persistent recurrence — plain launch, 128 blocks x 256 thr
    hipLaunchKernelGGL(gru_main, dim3(128), dim3(256), 0, stream,
                       x, Wih0, bih0, bhh0, bih1, bhh1, ws);

    // 3) linear head
    hipLaunchKernelGGL(head_kernel, dim3(256), dim3(64), 0, stream,
                       (const float*)ws, Wout, bout, out);
}

// Round 10
// 5407.723 us; speedup vs baseline: 1.8143x; 1.2632x over previous
//
#include <hip/hip_runtime.h>

typedef _Float16 half8 __attribute__((ext_vector_type(8)));
typedef float    f32x4 __attribute__((ext_vector_type(4)));

#define TT 512
#define BB 256
#define INDIM 8
#define HH 512

// ---- workspace layout ----
// floats [0, 131072)             : h1 final fp32 (head input, row-major [b][j])
// halves b16 = ws+131072 floats  : h0h[2] (2x131072), h1h[2] (2x131072)  (ROW-MAJOR [b][512])
//                                  Wpk [32 c][144 nl][512 k]  (c = 16-col chunk)
// bytes 6291456                  : flag0: 8 groups x 32 ints; flag1: 8 groups x 32 ints

__global__ void prep_kernel(const float* __restrict__ Whh0,
                            const float* __restrict__ Wih1,
                            const float* __restrict__ Whh1,
                            float* __restrict__ ws)
{
    const int NW = 32*144*512;                 // 2359296 packed weight halves
    _Float16* b16 = (_Float16*)(ws + 131072);
    _Float16* Wpk = b16 + 524288;
    int* flags = (int*)((char*)ws + 6291456);
    long long idx = (long long)blockIdx.x*256 + threadIdx.x;
    if (idx < NW) {
        int e   = (int)idx;
        int c   = e / (144*512);               // col-chunk 0..31 -> cols [c*16, c*16+16)
        int rem = e % (144*512);
        int nl  = rem >> 9;                    // 0..143 = g9*16 + m
        int k   = rem & 511;
        int g9  = nl >> 4;
        int m   = nl & 15;
        int j   = c*16 + m;
        float v;
        if      (g9 < 3) v = Whh0[(size_t)(g9*HH + j)*HH + k];
        else if (g9 < 6) v = Wih1[(size_t)((g9-3)*HH + j)*HH + k];
        else             v = Whh1[(size_t)((g9-6)*HH + j)*HH + k];
        Wpk[e] = (_Float16)v;
    } else if (idx < NW + 524288) {
        b16[idx - NW] = (_Float16)0.0f;        // zero all 4 f16 h buffers
    } else if (idx < NW + 524288 + 512) {
        flags[idx - NW - 524288] = 0;          // zero flag0 + flag1 slots
    } else if (idx < NW + 524288 + 512 + 131072) {
        ws[idx - (NW + 524288 + 512)] = 1.0e-3f;  // sentinel canary
    }
}

// 256 blocks x 256 threads, 1 block/CU (ALL 256 CUs), single launch.
// layer = blk>>7. lblk = blk&127: bg = lblk>>4 (32 batch rows), jg = lblk&15 (32 cols).
// TWO-STAGE PIPELINE (this round's structural change):
//  LAYER 0 (blocks 0-127), step p: a0 loads (h0[p-1]) -> gates 0-2 (LDS, all k) ->
//    h0 epilogue (x part in regs) -> store h0[p] -> drain -> publish flag0=p+1 ->
//    poll {flag0>=p+1, flag1>=p} -> next step.
//  LAYER 1 (blocks 128-255), step t (~1 step behind): poll {flag0>=t+1, flag1>=t} ->
//    load h0[t] + h1[t-1] -> gates 3-5 (LDS k<256 + L2 stream) + gates 6-8 (LDS all k)
//    -> h1 epilogue -> store h1[t] -> drain -> publish flag1=t+1.
// Safety: layer-0 writes h0[p+1] over h0[p-1] only after flag0>=p+1 (layer-0 peers
// consumed h0[p-1]) AND flag1>=p (layer-1 consumed h0[p-1] at its step p-1). Layer-1
// start-poll flag1>=t covers h1[t-1] availability and h1[t-2] overwrite (flag1=t is
// published only after step t-1 consumed h1[t-2]). Deadlock-free: layer-1 step p-1
// needs only flag0>=p (published); its flag1=p then satisfies layer-0's end-of-p poll.
// LDS rows padded to 520 halves (1040B == 4 dwords mod 32 banks) -> linear granule
// reads, consecutive-8-lane bank groups distinct, 2-way max (free) -> kills the
// 75.6M bank-conflict cycles of round 9's 1024B-stride layout.
__global__ void __launch_bounds__(256, 1)
gru_main(const float* __restrict__ x,
         const float* __restrict__ Wih0, const float* __restrict__ bih0,
         const float* __restrict__ bhh0, const float* __restrict__ bih1,
         const float* __restrict__ bhh1, float* __restrict__ ws)
{
    __shared__ __align__(16) _Float16 Wl[75264];   // 150528 B

    const int tid   = threadIdx.x;
    const int blk   = blockIdx.x;        // 0..255
    const int layer = blk >> 7;
    const int lblk  = blk & 127;
    const int jg    = lblk & 15;         // col group (32 cols = chunks 2jg, 2jg+1)
    const int bg    = lblk >> 4;         // batch group (32 rows)

    float* h1f = ws;
    _Float16* b16 = (_Float16*)(ws + 131072);
    _Float16* h0h[2] = { b16,          b16 + 131072 };
    _Float16* h1h[2] = { b16 + 262144, b16 + 393216 };
    const _Float16* Wpk = b16 + 524288;

    volatile int* flag0row = (volatile int*)((char*)ws + 6291456) + bg*32;
    volatile int* flag1row = (volatile int*)((char*)ws + 6291456) + 256 + bg*32;

    const int lane = tid & 63;
    const int wv   = tid >> 6;          // ct = wv&1 (col chunk), rt = wv>>1 (row tile)
    const int ct   = wv & 1;
    const int rt   = wv >> 1;
    const int m    = lane & 15;
    const int q    = lane >> 4;
    const int j    = jg*32 + ct*16 + m;
    const int bb   = bg*32 + rt*16;

    const _Float16* WpkB = Wpk + (size_t)(jg*2 + ct)*(144*512);

    // combined poll: lanes with psel=0 check flag0 >= step+1, psel=1 check flag1 >= step
    const int pidx = lane & 15;
    const int psel = (lane >> 4) & 1;
    volatile int* pollptr = psel ? (flag1row + pidx) : (flag0row + pidx);

    if (layer == 0) {
        // ================== LAYER 0: h0 recurrence (gates 0-2) ==================
        // LDS: gates 0-2, both chunks, all 512 k: [2 c][48 nl][520 halves]
        for (int t2 = tid; t2 < 2*48*64; t2 += 256) {
            int c = t2 / 3072, rem = t2 % 3072, nl = rem >> 6, g = rem & 63;
            *(float4*)&Wl[c*24960 + nl*520 + g*8] =
                *(const float4*)&Wpk[((size_t)(jg*2 + c)*144 + nl)*512 + g*8];
        }
        __syncthreads();
        const _Float16* WlA = Wl + ct*24960;

        float w0[3][8];
        #pragma unroll
        for (int g = 0; g < 3; ++g)
            #pragma unroll
            for (int kk = 0; kk < 8; ++kk)
                w0[g][kk] = Wih0[(size_t)(g*HH + j)*INDIM + kk];
        const float br0  = bih0[j]      + bhh0[j];
        const float bz0  = bih0[HH+j]   + bhh0[HH+j];
        const float bni0 = bih0[2*HH+j];
        const float bnh0 = bhh0[2*HH+j];

        float h0pr[4] = {0.f,0.f,0.f,0.f};

        f32x4 xA[4], xB[4];
        #pragma unroll
        for (int r = 0; r < 4; ++r) {
            const float* xv = x + (size_t)(bb + q*4 + r)*INDIM;
            asm volatile("global_load_dwordx4 %0, %1, off" : "=v"(xA[r]) : "v"(xv));
            asm volatile("global_load_dwordx4 %0, %1, off" : "=v"(xB[r]) : "v"(xv + 4));
        }

        for (int p = 0; p < TT; ++p) {
            const _Float16* a0base = h0h[(p+1)&1] + (size_t)(bb + m)*HH + q*8;  // h0[p-1]
            half8 a0s[16];
            #pragma unroll
            for (int s = 0; s < 16; ++s)
                asm volatile("global_load_dwordx4 %0, %1, off sc0 sc1"
                             : "=v"(a0s[s]) : "v"(a0base + s*32));
            asm volatile("s_waitcnt vmcnt(0)"
                : "+v"(a0s[0]),"+v"(a0s[1]),"+v"(a0s[2]),"+v"(a0s[3]),
                  "+v"(a0s[4]),"+v"(a0s[5]),"+v"(a0s[6]),"+v"(a0s[7]),
                  "+v"(a0s[8]),"+v"(a0s[9]),"+v"(a0s[10]),"+v"(a0s[11]),
                  "+v"(a0s[12]),"+v"(a0s[13]),"+v"(a0s[14]),"+v"(a0s[15]));
            asm volatile(""
                : "+v"(xA[0]),"+v"(xA[1]),"+v"(xA[2]),"+v"(xA[3]),
                  "+v"(xB[0]),"+v"(xB[1]),"+v"(xB[2]),"+v"(xB[3]));

            f32x4 acc0[3];
            #pragma unroll
            for (int g = 0; g < 3; ++g) acc0[g] = (f32x4){0.f,0.f,0.f,0.f};
            #pragma unroll
            for (int s = 0; s < 16; ++s) {
                #pragma unroll
                for (int g = 0; g < 3; ++g) {
                    half8 bf = *(const half8*)&WlA[(g*16+m)*520 + (s*4+q)*8];
                    acc0[g] = __builtin_amdgcn_mfma_f32_16x16x32_f16(a0s[s], bf, acc0[g], 0, 0, 0);
                }
            }

            _Float16* h0n = h0h[p&1];
            #pragma unroll
            for (int r = 0; r < 4; ++r) {
                const int b = bb + q*4 + r;
                f32x4 xa = xA[r], xb = xB[r];
                float gr = xa[0]*w0[0][0]+xa[1]*w0[0][1]+xa[2]*w0[0][2]+xa[3]*w0[0][3]
                         + xb[0]*w0[0][4]+xb[1]*w0[0][5]+xb[2]*w0[0][6]+xb[3]*w0[0][7];
                float gz = xa[0]*w0[1][0]+xa[1]*w0[1][1]+xa[2]*w0[1][2]+xa[3]*w0[1][3]
                         + xb[0]*w0[1][4]+xb[1]*w0[1][5]+xb[2]*w0[1][6]+xb[3]*w0[1][7];
                float gn = xa[0]*w0[2][0]+xa[1]*w0[2][1]+xa[2]*w0[2][2]+xa[3]*w0[2][3]
                         + xb[0]*w0[2][4]+xb[1]*w0[2][5]+xb[2]*w0[2][6]+xb[3]*w0[2][7];
                float rg = 1.f/(1.f + __expf(-(gr + acc0[0][r] + br0)));
                float zg = 1.f/(1.f + __expf(-(gz + acc0[1][r] + bz0)));
                float ng = tanhf(gn + bni0 + rg*(acc0[2][r] + bnh0));
                float hv = (1.f - zg)*ng + zg*h0pr[r];
                h0pr[r] = hv;
                _Float16 hv16 = (_Float16)hv;
                asm volatile("global_store_short %0, %1, off sc0 sc1"
                             :: "v"(h0n + (size_t)b*HH + j), "v"(hv16) : "memory");
            }
            asm volatile("s_waitcnt vmcnt(0)" ::: "memory");
            __syncthreads();
            if (tid == 0) flag0row[jg] = p + 1;          // h0[p] published

            // x prefetch for p+1 (in flight across the poll)
            {
                const size_t psafe = (p + 1 < TT) ? (size_t)(p + 1) : (size_t)(TT - 1);
                #pragma unroll
                for (int r = 0; r < 4; ++r) {
                    const float* xv = x + (psafe*BB + (size_t)(bb + q*4 + r))*INDIM;
                    asm volatile("global_load_dwordx4 %0, %1, off" : "=v"(xA[r]) : "v"(xv));
                    asm volatile("global_load_dwordx4 %0, %1, off" : "=v"(xB[r]) : "v"(xv + 4));
                }
            }
            if (p < TT-1) {
                // gate step p+1: flag0 >= p+1 (peers consumed h0[p-1]; h0[p] readable),
                //                flag1 >= p   (layer-1 consumed h0[p-1])
                if (tid < 64) {
                    const int tgt = p + 1 - psel;
                    while (true) {
                        int v = *pollptr;
                        if (__all(v >= tgt)) break;
                        __builtin_amdgcn_s_sleep(1);
                    }
                }
                __syncthreads();
            }
        }
    } else {
        // ================== LAYER 1: h1 recurrence (gates 3-8) ==================
        // LDS: gates 6-8 all k [2 c][48 nl][520]; gates 3-5 k<256 [2 c][48 nl][264]
        for (int t2 = tid; t2 < 2*48*64; t2 += 256) {
            int c = t2 / 3072, rem = t2 % 3072, nl = rem >> 6, g = rem & 63;
            *(float4*)&Wl[c*24960 + nl*520 + g*8] =
                *(const float4*)&Wpk[((size_t)(jg*2 + c)*144 + 96 + nl)*512 + g*8];
        }
        for (int t2 = tid; t2 < 2*48*32; t2 += 256) {
            int c = t2 / 1536, rem = t2 % 1536, nl = rem >> 5, g = rem & 31;
            *(float4*)&Wl[49920 + c*12672 + nl*264 + g*8] =
                *(const float4*)&Wpk[((size_t)(jg*2 + c)*144 + 48 + nl)*512 + g*8];
        }
        __syncthreads();
        const _Float16* WlC = Wl + ct*24960;            // gates 6-8
        const _Float16* WlB = Wl + 49920 + ct*12672;    // gates 3-5, k<256

        const float br1  = bih1[j]      + bhh1[j];
        const float bz1  = bih1[HH+j]   + bhh1[HH+j];
        const float bni1 = bih1[2*HH+j];
        const float bnh1 = bhh1[2*HH+j];

        float h1pr[4] = {0.f,0.f,0.f,0.f};

        for (int t = 0; t < TT; ++t) {
            // gate: flag0 >= t+1 (h0[t] ready), flag1 >= t (h1[t-1] ready, h1[t-2] free)
            if (tid < 64) {
                const int tgt = t + 1 - psel;
                while (true) {
                    int v = *pollptr;
                    if (__all(v >= tgt)) break;
                    __builtin_amdgcn_s_sleep(1);
                }
            }
            __syncthreads();

            const _Float16* aXbase = h0h[t&1]     + (size_t)(bb + m)*HH + q*8;  // h0[t]
            const _Float16* a1base = h1h[(t+1)&1] + (size_t)(bb + m)*HH + q*8;  // h1[t-1]
            half8 aXs[16], a1s[16];
            #pragma unroll
            for (int s = 0; s < 16; ++s) {
                asm volatile("global_load_dwordx4 %0, %1, off sc0 sc1"
                             : "=v"(aXs[s]) : "v"(aXbase + s*32));
                asm volatile("global_load_dwordx4 %0, %1, off sc0 sc1"
                             : "=v"(a1s[s]) : "v"(a1base + s*32));
            }
            asm volatile("s_waitcnt vmcnt(0)"
                : "+v"(aXs[0]),"+v"(aXs[1]),"+v"(aXs[2]),"+v"(aXs[3]),
                  "+v"(aXs[4]),"+v"(aXs[5]),"+v"(aXs[6]),"+v"(aXs[7]),
                  "+v"(aXs[8]),"+v"(aXs[9]),"+v"(aXs[10]),"+v"(aXs[11]),
                  "+v"(aXs[12]),"+v"(aXs[13]),"+v"(aXs[14]),"+v"(aXs[15]));
            asm volatile(""
                : "+v"(a1s[0]),"+v"(a1s[1]),"+v"(a1s[2]),"+v"(a1s[3]),
                  "+v"(a1s[4]),"+v"(a1s[5]),"+v"(a1s[6]),"+v"(a1s[7]),
                  "+v"(a1s[8]),"+v"(a1s[9]),"+v"(a1s[10]),"+v"(a1s[11]),
                  "+v"(a1s[12]),"+v"(a1s[13]),"+v"(a1s[14]),"+v"(a1s[15]));

            f32x4 acc[6];   // [0..2] gates 3-5 (Wih1*h0[t]); [3..5] gates 6-8 (Whh1*h1[t-1])
            #pragma unroll
            for (int g = 0; g < 6; ++g) acc[g] = (f32x4){0.f,0.f,0.f,0.f};

            // gates 3-5: k-steps 0-7 from LDS, 8-15 streamed from L2 (pipelined)
            #pragma unroll
            for (int s = 0; s < 8; ++s) {
                #pragma unroll
                for (int gg = 0; gg < 3; ++gg) {
                    half8 bf = *(const half8*)&WlB[(gg*16+m)*264 + (s*4+q)*8];
                    acc[gg] = __builtin_amdgcn_mfma_f32_16x16x32_f16(aXs[s], bf, acc[gg], 0, 0, 0);
                }
            }
            half8 nb[3];
            #pragma unroll
            for (int gg = 0; gg < 3; ++gg)
                nb[gg] = *(const half8*)&WpkB[(size_t)(48 + gg*16 + m)*512 + 8*32 + q*8];
            #pragma unroll
            for (int s = 8; s < 16; ++s) {
                half8 cb[3];
                #pragma unroll
                for (int gg = 0; gg < 3; ++gg) cb[gg] = nb[gg];
                if (s < 15) {
                    #pragma unroll
                    for (int gg = 0; gg < 3; ++gg)
                        nb[gg] = *(const half8*)&WpkB[(size_t)(48 + gg*16 + m)*512 + (s+1)*32 + q*8];
                }
                #pragma unroll
                for (int gg = 0; gg < 3; ++gg)
                    acc[gg] = __builtin_amdgcn_mfma_f32_16x16x32_f16(aXs[s], cb[gg], acc[gg], 0, 0, 0);
            }
            // gates 6-8: all 16 k-steps from LDS
            #pragma unroll
            for (int s = 0; s < 16; ++s) {
                #pragma unroll
                for (int gg = 0; gg < 3; ++gg) {
                    half8 bf = *(const half8*)&WlC[(gg*16+m)*520 + (s*4+q)*8];
                    acc[3+gg] = __builtin_amdgcn_mfma_f32_16x16x32_f16(a1s[s], bf, acc[3+gg], 0, 0, 0);
                }
            }

            _Float16* h1n = h1h[t&1];
            #pragma unroll
            for (int r = 0; r < 4; ++r) {
                const int b = bb + q*4 + r;
                float rg = 1.f/(1.f + __expf(-(acc[0][r] + acc[3][r] + br1)));
                float zg = 1.f/(1.f + __expf(-(acc[1][r] + acc[4][r] + bz1)));
                float ng = tanhf(acc[2][r] + bni1 + rg*(acc[5][r] + bnh1));
                float hv = (1.f - zg)*ng + zg*h1pr[r];
                h1pr[r] = hv;
                _Float16 hv16 = (_Float16)hv;
                asm volatile("global_store_short %0, %1, off sc0 sc1"
                             :: "v"(h1n + (size_t)b*HH + j), "v"(hv16) : "memory");
                if (t == TT-1) h1f[(size_t)b*HH + j] = hv;   // kernel-boundary flush
            }
            asm volatile("s_waitcnt vmcnt(0)" ::: "memory");
            __syncthreads();
            if (tid == 0) flag1row[jg] = t + 1;          // h1[t] published
        }
    }
}

__global__ void head_kernel(const float* __restrict__ ws,
                            const float* __restrict__ Wout,
                            const float* __restrict__ bout,
                            float* __restrict__ out)
{
    const float* h1 = ws;               // h1[511] fp32
    int b = blockIdx.x;
    int lane = threadIdx.x;             // 64
    for (int o = 0; o < 5; ++o) {
        float s = 0.f;
        for (int k = lane; k < HH; k += 64)
            s += h1[(size_t)b*HH + k] * Wout[(size_t)o*HH + k];
        for (int off = 32; off > 0; off >>= 1)
            s += __shfl_xor(s, off, 64);
        if (lane == 0) out[b*5 + o] = s + bout[o];
    }
}

extern "C" void kernel_launch(void* const* d_in, const int* in_sizes, int n_in,
                              void* d_out, int out_size, void* d_ws, size_t ws_size,
                              hipStream_t stream) {
    const float* x    = (const float*)d_in[0];
    const float* Wih0 = (const float*)d_in[1];
    const float* Whh0 = (const float*)d_in[2];
    const float* bih0 = (const float*)d_in[3];
    const float* bhh0 = (const float*)d_in[4];
    const float* Wih1 = (const float*)d_in[5];
    const float* Whh1 = (const float*)d_in[6];
    const float* bih1 = (const float*)d_in[7];
    const float* bhh1 = (const float*)d_in[8];
    const float* Wout = (const float*)d_in[9];
    const float* bout = (const float*)d_in[10];
    float* out = (float*)d_out;
    float* ws  = (float*)d_ws;   // needs ~6.3 MB

    // 1) pack weights to f16 + zero f16 state + zero flags + sentinel h1f
    const long long total = 32LL*144*512 + 524288 + 512 + 131072;
    int pblocks = (int)((total + 255) / 256);
    hipLaunchKernelGGL(prep_kernel, dim3(pblocks), dim3(256), 0, stream,
                       Whh0, Wih1, Whh1, ws);

    // 2) persistent recurrence — 256 blocks (128 layer-0 + 128 layer-1), 1 block/CU
    hipLaunchKernelGGL(gru_main, dim3(256), dim3(256), 0, stream,
                       x, Wih0, bih0, bhh0, bih1, bhh1, ws);

    // 3) linear head
    hipLaunchKernelGGL(head_kernel, dim3(256), dim3(64), 0, stream,
                       (const float*)ws, Wout, bout, out);
}